// Round 3
// baseline (231.098 us; speedup 1.0000x reference)
//
#include <hip/hip_runtime.h>
#include <stdint.h>

// B=2, H=16, L=2048, D=64 causal attention, fp32 in/out.
#define B_ 2
#define H_ 16
#define L_ 2048
#define D_ 64
#define BN 64   // KV rows per tile; also q rows per strip

typedef __attribute__((ext_vector_type(8))) _Float16 half8;
typedef __attribute__((ext_vector_type(4))) _Float16 half4;
typedef __attribute__((ext_vector_type(4))) float    f32x4;

// 512-thread block = strip pair (p, 31-p) x two kv-parity wave groups.
//   Waves 0-3 (g=0): even tiles; waves 4-7 (g=1): odd tiles. Every wave
//   computes BOTH strips per tile (strip A while t <= p), sharing K/V reads.
//   Work per group = 16-17 tile-units, uniform across ALL waves of ALL blocks.
// Why: rounds 1/2 both cost ~2030 cyc/tile-unit vs ~350 cyc of issue work —
//   latency-bound. Round 2's pairing exposed only 2048 wave-units on 1024
//   SIMDs (2 waves/SIMD, 16% occupancy). The parity split doubles the
//   independent wave count: 2 blocks/CU x 8 waves = 4 waves/SIMD, no tail.
// LDS: 4 buffers (buf = t&3), 69,632 B -> exactly 2 blocks/CU. Staging halves
//   are group-aligned (tid>>8 == g): half g stages tiles of parity g, so the
//   stage targets {2u+2,2u+3} never alias compute buffers {2u,2u+1}; the
//   single per-iteration barrier fences both (stage's prior readers ran in
//   iteration u-1; compute's data was staged in u-1).
// Partials (o, lsum) combined via in-LDS exchange: group 0 finalizes strip A,
//   group 1 strip B (all-positive lsum adds; fp32 o adds — error still
//   dominated by fp16 P/V quantization).
// lsum kept as 4 accumulators: round 2 had a 32-long dependent fadd chain per
//   tile; 4 chains of 8 hide under MFMA issue.
// blockIdx decode (assumes round-robin i%8 -> XCD): bh = ((i>>3)&3)*8+(i&7)
//   gives each XCD all 16 pairs of 4 fixed bh's -> K/V stream L2-local.

__global__ __launch_bounds__(512, 4) void fa_fwd(
    const float* __restrict__ Q, const float* __restrict__ K,
    const float* __restrict__ V, float* __restrict__ O)
{
    const int i  = blockIdx.x;
    const int bh = ((i >> 3) & 3) * 8 + (i & 7);
    const int p  = i >> 5;               // 0..15
    const int dA = p;                    // small strip diagonal
    const int dB = 31 - p;               // large strip diagonal (>= 16)

    const int tid  = threadIdx.x;
    const int wv   = tid >> 6;           // 0..7
    const int g    = wv >> 2;            // kv parity group (== tid>>8)
    const int wrow = wv & 3;             // 16-row band within each strip
    const int lane = tid & 63;
    const int l16  = lane & 15;
    const int quad = lane >> 4;

    const size_t base = (size_t)bh * (size_t)(L_ * D_);
    const float* Qb = Q + base;
    const float* Kb = K + base;
    const float* Vb = V + base;
    float*       Ob = O + base;

    // 4 buffers: tile t lives in buf t&3. 69,632 B total.
    __shared__ __align__(16) _Float16 Klds [4][BN][72];  // row-major K
    __shared__ __align__(16) _Float16 Vtlds[4][D_][64];  // V^T, 8B-block swizzled

    // ---- staging: 256-thread half g stages tiles of parity g ----
    const int sub   = tid & 255;
    const int srow  = sub >> 4;          // K: row 0..15 (x4)
    const int scol  = (sub & 15) * 4;    // K: col
    const int vw    = sub >> 6;          // V: 16-row band 0..3
    const int vlane = sub & 63;          // V: d = vlane

    float fk[16];  // K prefetch regs (float4[4])
    float fv[16];  // V prefetch regs (16 scalars)

    auto prefetch = [&](int kv0) {
        float4* kq = (float4*)fk;
        const float* kp = Kb + (size_t)kv0 * D_ + (size_t)sub * 4;
        #pragma unroll
        for (int u = 0; u < 4; ++u) kq[u] = *(const float4*)(kp + u * 1024);
        const float* vp = Vb + (size_t)(kv0 + vw * 16) * D_ + vlane;
        #pragma unroll
        for (int rr = 0; rr < 16; ++rr) fv[rr] = vp[rr * D_];
    };

    auto stage = [&](int buf) {
        const float4* kq = (const float4*)fk;
        #pragma unroll
        for (int u = 0; u < 4; ++u) {
            half4 ks;
            ks[0] = (_Float16)kq[u].x; ks[1] = (_Float16)kq[u].y;
            ks[2] = (_Float16)kq[u].z; ks[3] = (_Float16)kq[u].w;
            *(half4*)&Klds[buf][u * 16 + srow][scol] = ks;
        }
        #pragma unroll
        for (int c = 0; c < 4; ++c) {
            half4 vs;
            vs[0] = (_Float16)fv[4 * c + 0]; vs[1] = (_Float16)fv[4 * c + 1];
            vs[2] = (_Float16)fv[4 * c + 2]; vs[3] = (_Float16)fv[4 * c + 3];
            // kv>>2 = 4*vw + c; pos = (kv>>2 + d + 4*(d>>4)) & 15, d = vlane
            const int pp = ((4 * vw + c) + vlane + 4 * (vlane >> 4)) & 15;
            *(half4*)((char*)&Vtlds[buf][vlane][0] + pp * 8) = vs;
        }
    };

    // ---- per-strip state ----
    // Q fragment: B-operand of S^T = K.Q^T; per-lane Q[q0+wrow*16+l16][c*32+quad*8+j]
    half8 qfA[2], qfB[2];
    const int qA_abs = dA * 64 + wrow * 16 + l16;
    const int qB_abs = dB * 64 + wrow * 16 + l16;
    auto loadQ = [&](half8* qf, int q_abs) {
        #pragma unroll
        for (int c = 0; c < 2; ++c) {
            const float* pq = Qb + (size_t)q_abs * D_ + c * 32 + quad * 8;
            float4 a = *(const float4*)(pq);
            float4 b = *(const float4*)(pq + 4);
            half8 f;
            f[0] = (_Float16)a.x; f[1] = (_Float16)a.y;
            f[2] = (_Float16)a.z; f[3] = (_Float16)a.w;
            f[4] = (_Float16)b.x; f[5] = (_Float16)b.y;
            f[6] = (_Float16)b.z; f[7] = (_Float16)b.w;
            qf[c] = f;
        }
    };
    loadQ(qfA, qA_abs);
    loadQ(qfB, qB_abs);

    f32x4 oA[4], oB[4];
    #pragma unroll
    for (int n = 0; n < 4; ++n) {
        oA[n] = (f32x4){0.f, 0.f, 0.f, 0.f};
        oB[n] = (f32x4){0.f, 0.f, 0.f, 0.f};
    }
    f32x4 lsA4 = (f32x4){0.f, 0.f, 0.f, 0.f};
    f32x4 lsB4 = (f32x4){0.f, 0.f, 0.f, 0.f};

    const float cs = 0.18033688011112042f; // (1/8) * log2(e)

    // ---- pipeline prologue (dB >= 16, tiles 0..3 always exist) ----
    prefetch(g * BN);          // tile g
    stage(g);                  // buf g
    prefetch((2 + g) * BN);    // tile 2+g
    __syncthreads();

    // ---- main loop: one barrier per TWO tiles ----
    const int nIter = (dB + 2) >> 1;     // ceil((dB+1)/2)
    for (int u = 0; u < nIter; ++u) {
        const int ts = 2 * u + 2 + g;          // stage (regs prefetched last iter)
        if (ts <= dB) stage(ts & 3);
        const int tp = 2 * u + 4 + g;          // issue next prefetch; lands
        if (tp <= dB) prefetch(tp * BN);       // during compute below

        const int t = 2 * u + g;               // my group's tile
        if (t <= dB) {
            const int buf = t & 3;
            const int kv0 = t * BN;
            if (t <= dA) {
                // ---- both strips, shared K/V LDS reads ----
                f32x4 sB[4], sA[4];
                #pragma unroll
                for (int n = 0; n < 4; ++n) {
                    f32x4 aB = (f32x4){0.f, 0.f, 0.f, 0.f};
                    f32x4 aA = (f32x4){0.f, 0.f, 0.f, 0.f};
                    #pragma unroll
                    for (int c = 0; c < 2; ++c) {
                        half8 kf = *(const half8*)&Klds[buf][n * 16 + l16][c * 32 + quad * 8];
                        aB = __builtin_amdgcn_mfma_f32_16x16x32_f16(kf, qfB[c], aB, 0, 0, 0);
                        aA = __builtin_amdgcn_mfma_f32_16x16x32_f16(kf, qfA[c], aA, 0, 0, 0);
                    }
                    sB[n] = aB; sA[n] = aA;
                }
                if (t == dA) {                 // strip A diagonal mask
                    #pragma unroll
                    for (int n = 0; n < 4; ++n) {
                        const int kvr = kv0 + n * 16 + quad * 4;
                        #pragma unroll
                        for (int r = 0; r < 4; ++r)
                            if (kvr + r > qA_abs) sA[n][r] = -1e30f;
                    }
                }
                half4 phB[4], phA[4];
                #pragma unroll
                for (int n = 0; n < 4; ++n)
                    #pragma unroll
                    for (int r = 0; r < 4; ++r) {
                        const float eB = __builtin_amdgcn_exp2f(sB[n][r] * cs);
                        lsB4[r] += eB; phB[n][r] = (_Float16)eB;
                        const float eA = __builtin_amdgcn_exp2f(sA[n][r] * cs);
                        lsA4[r] += eA; phA[n][r] = (_Float16)eA;
                    }
                #pragma unroll
                for (int nt = 0; nt < 4; ++nt) {
                    const char* row = (const char*)&Vtlds[buf][nt * 16 + l16][0];
                    #pragma unroll
                    for (int nk = 0; nk < 4; ++nk) {
                        const int pp = (4 * nk + quad + l16 + 4 * nt) & 15;
                        half4 bv = *(const half4*)(row + pp * 8);
                        oB[nt] = __builtin_amdgcn_mfma_f32_16x16x16f16(phB[nk], bv, oB[nt], 0, 0, 0);
                        oA[nt] = __builtin_amdgcn_mfma_f32_16x16x16f16(phA[nk], bv, oA[nt], 0, 0, 0);
                    }
                }
            } else {
                // ---- strip B only ----
                f32x4 sB[4];
                #pragma unroll
                for (int n = 0; n < 4; ++n) {
                    f32x4 aB = (f32x4){0.f, 0.f, 0.f, 0.f};
                    #pragma unroll
                    for (int c = 0; c < 2; ++c) {
                        half8 kf = *(const half8*)&Klds[buf][n * 16 + l16][c * 32 + quad * 8];
                        aB = __builtin_amdgcn_mfma_f32_16x16x32_f16(kf, qfB[c], aB, 0, 0, 0);
                    }
                    sB[n] = aB;
                }
                if (t == dB) {                 // strip B diagonal mask
                    #pragma unroll
                    for (int n = 0; n < 4; ++n) {
                        const int kvr = kv0 + n * 16 + quad * 4;
                        #pragma unroll
                        for (int r = 0; r < 4; ++r)
                            if (kvr + r > qB_abs) sB[n][r] = -1e30f;
                    }
                }
                half4 phB[4];
                #pragma unroll
                for (int n = 0; n < 4; ++n)
                    #pragma unroll
                    for (int r = 0; r < 4; ++r) {
                        const float eB = __builtin_amdgcn_exp2f(sB[n][r] * cs);
                        lsB4[r] += eB; phB[n][r] = (_Float16)eB;
                    }
                #pragma unroll
                for (int nt = 0; nt < 4; ++nt) {
                    const char* row = (const char*)&Vtlds[buf][nt * 16 + l16][0];
                    #pragma unroll
                    for (int nk = 0; nk < 4; ++nk) {
                        const int pp = (4 * nk + quad + l16 + 4 * nt) & 15;
                        half4 bv = *(const half4*)(row + pp * 8);
                        oB[nt] = __builtin_amdgcn_mfma_f32_16x16x16f16(phB[nk], bv, oB[nt], 0, 0, 0);
                    }
                }
            }
        }
        __syncthreads();   // fences staged data for u+1 AND buffer reuse at u+1
    }

    // ---- combine parity partials via LDS, normalize, store ----
    // group 0 finalizes strip A; group 1 finalizes strip B.
    // Exchange: group 1 writes its (oA, lsA); group 0 writes its (oB, lsB).
    // Layout: [strip(A=0,B=1)][wrow][lane][17] floats, stride 17 = conflict-free.
    float* ex = (float*)&Klds[0][0][0];      // reuse: 34,816 B <= 36,864 B
    const int slotsz = 64 * 17;
    {
        float* wb = ex + (g ? 0 : 4 * slotsz) + wrow * slotsz + lane * 17;
        const f32x4* po = g ? oA : oB;
        const f32x4  l4 = g ? lsA4 : lsB4;
        #pragma unroll
        for (int nt = 0; nt < 4; ++nt)
            #pragma unroll
            for (int r = 0; r < 4; ++r) wb[nt * 4 + r] = po[nt][r];
        wb[16] = (l4[0] + l4[1]) + (l4[2] + l4[3]);
    }
    __syncthreads();
    {
        const float* rb = ex + (g ? 4 * slotsz : 0) + wrow * slotsz + lane * 17;
        const f32x4* mine = g ? oB : oA;
        const f32x4  m4   = g ? lsB4 : lsA4;
        f32x4 o[4];
        #pragma unroll
        for (int nt = 0; nt < 4; ++nt)
            #pragma unroll
            for (int r = 0; r < 4; ++r) o[nt][r] = mine[nt][r] + rb[nt * 4 + r];
        float v = ((m4[0] + m4[1]) + (m4[2] + m4[3])) + rb[16];
        v += __shfl_xor(v, 16, 64);
        v += __shfl_xor(v, 32, 64);
        float linv[4];
        #pragma unroll
        for (int r = 0; r < 4; ++r)
            linv[r] = 1.0f / __shfl(v, quad * 4 + r, 64);
        const int q0s = (g ? dB : dA) * 64;
        const int qr0 = q0s + wrow * 16 + quad * 4;
        #pragma unroll
        for (int nt = 0; nt < 4; ++nt)
            #pragma unroll
            for (int r = 0; r < 4; ++r)
                Ob[(size_t)(qr0 + r) * D_ + nt * 16 + l16] = o[nt][r] * linv[r];
    }
}

extern "C" void kernel_launch(void* const* d_in, const int* in_sizes, int n_in,
                              void* d_out, int out_size, void* d_ws, size_t ws_size,
                              hipStream_t stream) {
    const float* Q = (const float*)d_in[0];
    const float* K = (const float*)d_in[1];
    const float* V = (const float*)d_in[2];
    float*       O = (float*)d_out;
    fa_fwd<<<dim3(16 * B_ * H_), dim3(512), 0, stream>>>(Q, K, V, O);
}

// Round 4
// 126.941 us; speedup vs baseline: 1.8205x; 1.8205x over previous
//
#include <hip/hip_runtime.h>
#include <stdint.h>

// B=2, H=16, L=2048, D=64 causal attention, fp32 in/out.
#define B_ 2
#define H_ 16
#define L_ 2048
#define D_ 64
#define BN 64   // KV rows per tile; also q rows per strip

typedef __attribute__((ext_vector_type(8))) _Float16 half8;
typedef __attribute__((ext_vector_type(4))) _Float16 half4;
typedef __attribute__((ext_vector_type(4))) float    f32x4;

// 512-thread block = strip pair (p, 31-p) x two kv-parity wave groups.
//   Waves 0-3 (g=0): even tiles; waves 4-7 (g=1): odd tiles. Every wave
//   computes BOTH strips per tile (strip A while t <= p), sharing K/V reads.
//   Work per group = 16-17 tile-units, uniform across ALL waves of ALL blocks.
//   -> 2 blocks/CU x 8 waves = 16 waves/CU (4/SIMD), no triangular tail.
//
// ROUND-3 POST-MORTEM (do not regress this): __launch_bounds__'s second arg
// on this hipcc is MIN BLOCKS PER CU (CUDA semantics), NOT waves-per-EU.
// (512,4) capped VGPRs at 64 (4 blk x 8 waves = 32 waves/CU) -> ~60 regs of
// state spilled to scratch: WRITE_SIZE 16->158 MB, MfmaUtil 6%, 160 us.
// Evidence: r0 (512,4) cap64/used52 ok; r2 (256,2) cap256/used108 ok.
// (512,2) = 16 waves/CU -> 128-VGPR cap; this kernel peaks ~120 live.
//
// LDS: 4 buffers (buf = t&3), 69,632 B -> exactly 2 blocks/CU. Staging halves
//   are group-aligned (tid>>8 == g): half g stages tiles of parity g, so the
//   stage targets {2u+2,2u+3} never alias compute buffers {2u,2u+1}; the
//   single per-iteration barrier fences both (stage's prior readers ran in
//   iteration u-1; compute's data was staged in u-1).
// Partials (o, lsum) combined via in-LDS exchange: group 0 finalizes strip A,
//   group 1 strip B (all-positive lsum adds; fp32 o adds — error still
//   dominated by fp16 P/V quantization).
// blockIdx decode (assumes round-robin i%8 -> XCD): bh = ((i>>3)&3)*8+(i&7)
//   gives each XCD all 16 pairs of 4 fixed bh's -> K/V stream L2-local.

__global__ __launch_bounds__(512, 2) void fa_fwd(
    const float* __restrict__ Q, const float* __restrict__ K,
    const float* __restrict__ V, float* __restrict__ O)
{
    const int i  = blockIdx.x;
    const int bh = ((i >> 3) & 3) * 8 + (i & 7);
    const int p  = i >> 5;               // 0..15
    const int dA = p;                    // small strip diagonal
    const int dB = 31 - p;               // large strip diagonal (>= 16)

    const int tid  = threadIdx.x;
    const int wv   = tid >> 6;           // 0..7
    const int g    = wv >> 2;            // kv parity group (== tid>>8)
    const int wrow = wv & 3;             // 16-row band within each strip
    const int lane = tid & 63;
    const int l16  = lane & 15;
    const int quad = lane >> 4;

    const size_t base = (size_t)bh * (size_t)(L_ * D_);
    const float* Qb = Q + base;
    const float* Kb = K + base;
    const float* Vb = V + base;
    float*       Ob = O + base;

    // 4 buffers: tile t lives in buf t&3. 69,632 B total.
    __shared__ __align__(16) _Float16 Klds [4][BN][72];  // row-major K
    __shared__ __align__(16) _Float16 Vtlds[4][D_][64];  // V^T, 8B-block swizzled

    // ---- staging: 256-thread half g stages tiles of parity g ----
    const int sub   = tid & 255;
    const int srow  = sub >> 4;          // K: row 0..15 (x4)
    const int scol  = (sub & 15) * 4;    // K: col
    const int vw    = sub >> 6;          // V: 16-row band 0..3
    const int vlane = sub & 63;          // V: d = vlane

    float fk[16];  // K prefetch regs (float4[4])
    float fv[16];  // V prefetch regs (16 scalars)

    auto prefetch = [&](int kv0) {
        float4* kq = (float4*)fk;
        const float* kp = Kb + (size_t)kv0 * D_ + (size_t)sub * 4;
        #pragma unroll
        for (int u = 0; u < 4; ++u) kq[u] = *(const float4*)(kp + u * 1024);
        const float* vp = Vb + (size_t)(kv0 + vw * 16) * D_ + vlane;
        #pragma unroll
        for (int rr = 0; rr < 16; ++rr) fv[rr] = vp[rr * D_];
    };

    auto stage = [&](int buf) {
        const float4* kq = (const float4*)fk;
        #pragma unroll
        for (int u = 0; u < 4; ++u) {
            half4 ks;
            ks[0] = (_Float16)kq[u].x; ks[1] = (_Float16)kq[u].y;
            ks[2] = (_Float16)kq[u].z; ks[3] = (_Float16)kq[u].w;
            *(half4*)&Klds[buf][u * 16 + srow][scol] = ks;
        }
        #pragma unroll
        for (int c = 0; c < 4; ++c) {
            half4 vs;
            vs[0] = (_Float16)fv[4 * c + 0]; vs[1] = (_Float16)fv[4 * c + 1];
            vs[2] = (_Float16)fv[4 * c + 2]; vs[3] = (_Float16)fv[4 * c + 3];
            // kv>>2 = 4*vw + c; pos = (kv>>2 + d + 4*(d>>4)) & 15, d = vlane
            const int pp = ((4 * vw + c) + vlane + 4 * (vlane >> 4)) & 15;
            *(half4*)((char*)&Vtlds[buf][vlane][0] + pp * 8) = vs;
        }
    };

    // ---- per-strip state ----
    // Q fragment: B-operand of S^T = K.Q^T; per-lane Q[q0+wrow*16+l16][c*32+quad*8+j]
    half8 qfA[2], qfB[2];
    const int qA_abs = dA * 64 + wrow * 16 + l16;
    const int qB_abs = dB * 64 + wrow * 16 + l16;
    auto loadQ = [&](half8* qf, int q_abs) {
        #pragma unroll
        for (int c = 0; c < 2; ++c) {
            const float* pq = Qb + (size_t)q_abs * D_ + c * 32 + quad * 8;
            float4 a = *(const float4*)(pq);
            float4 b = *(const float4*)(pq + 4);
            half8 f;
            f[0] = (_Float16)a.x; f[1] = (_Float16)a.y;
            f[2] = (_Float16)a.z; f[3] = (_Float16)a.w;
            f[4] = (_Float16)b.x; f[5] = (_Float16)b.y;
            f[6] = (_Float16)b.z; f[7] = (_Float16)b.w;
            qf[c] = f;
        }
    };
    loadQ(qfA, qA_abs);
    loadQ(qfB, qB_abs);

    f32x4 oA[4], oB[4];
    #pragma unroll
    for (int n = 0; n < 4; ++n) {
        oA[n] = (f32x4){0.f, 0.f, 0.f, 0.f};
        oB[n] = (f32x4){0.f, 0.f, 0.f, 0.f};
    }
    f32x4 lsA4 = (f32x4){0.f, 0.f, 0.f, 0.f};
    f32x4 lsB4 = (f32x4){0.f, 0.f, 0.f, 0.f};

    const float cs = 0.18033688011112042f; // (1/8) * log2(e)

    // ---- pipeline prologue (dB >= 16, tiles 0..3 always exist) ----
    prefetch(g * BN);          // tile g
    stage(g);                  // buf g
    prefetch((2 + g) * BN);    // tile 2+g
    __syncthreads();

    // ---- main loop: one barrier per TWO tiles ----
    const int nIter = (dB + 2) >> 1;     // ceil((dB+1)/2)
    for (int u = 0; u < nIter; ++u) {
        const int ts = 2 * u + 2 + g;          // stage (regs prefetched last iter)
        if (ts <= dB) stage(ts & 3);
        const int tp = 2 * u + 4 + g;          // issue next prefetch; lands
        if (tp <= dB) prefetch(tp * BN);       // during compute below

        const int t = 2 * u + g;               // my group's tile
        if (t <= dB) {
            const int buf = t & 3;
            const int kv0 = t * BN;
            if (t <= dA) {
                // ---- both strips, shared K/V LDS reads ----
                f32x4 sB[4], sA[4];
                #pragma unroll
                for (int n = 0; n < 4; ++n) {
                    f32x4 aB = (f32x4){0.f, 0.f, 0.f, 0.f};
                    f32x4 aA = (f32x4){0.f, 0.f, 0.f, 0.f};
                    #pragma unroll
                    for (int c = 0; c < 2; ++c) {
                        half8 kf = *(const half8*)&Klds[buf][n * 16 + l16][c * 32 + quad * 8];
                        aB = __builtin_amdgcn_mfma_f32_16x16x32_f16(kf, qfB[c], aB, 0, 0, 0);
                        aA = __builtin_amdgcn_mfma_f32_16x16x32_f16(kf, qfA[c], aA, 0, 0, 0);
                    }
                    sB[n] = aB; sA[n] = aA;
                }
                if (t == dA) {                 // strip A diagonal mask
                    #pragma unroll
                    for (int n = 0; n < 4; ++n) {
                        const int kvr = kv0 + n * 16 + quad * 4;
                        #pragma unroll
                        for (int r = 0; r < 4; ++r)
                            if (kvr + r > qA_abs) sA[n][r] = -1e30f;
                    }
                }
                half4 phB[4], phA[4];
                #pragma unroll
                for (int n = 0; n < 4; ++n)
                    #pragma unroll
                    for (int r = 0; r < 4; ++r) {
                        const float eB = __builtin_amdgcn_exp2f(sB[n][r] * cs);
                        lsB4[r] += eB; phB[n][r] = (_Float16)eB;
                        const float eA = __builtin_amdgcn_exp2f(sA[n][r] * cs);
                        lsA4[r] += eA; phA[n][r] = (_Float16)eA;
                    }
                #pragma unroll
                for (int nt = 0; nt < 4; ++nt) {
                    const char* row = (const char*)&Vtlds[buf][nt * 16 + l16][0];
                    #pragma unroll
                    for (int nk = 0; nk < 4; ++nk) {
                        const int pp = (4 * nk + quad + l16 + 4 * nt) & 15;
                        half4 bv = *(const half4*)(row + pp * 8);
                        oB[nt] = __builtin_amdgcn_mfma_f32_16x16x16f16(phB[nk], bv, oB[nt], 0, 0, 0);
                        oA[nt] = __builtin_amdgcn_mfma_f32_16x16x16f16(phA[nk], bv, oA[nt], 0, 0, 0);
                    }
                }
            } else {
                // ---- strip B only ----
                f32x4 sB[4];
                #pragma unroll
                for (int n = 0; n < 4; ++n) {
                    f32x4 aB = (f32x4){0.f, 0.f, 0.f, 0.f};
                    #pragma unroll
                    for (int c = 0; c < 2; ++c) {
                        half8 kf = *(const half8*)&Klds[buf][n * 16 + l16][c * 32 + quad * 8];
                        aB = __builtin_amdgcn_mfma_f32_16x16x32_f16(kf, qfB[c], aB, 0, 0, 0);
                    }
                    sB[n] = aB;
                }
                if (t == dB) {                 // strip B diagonal mask
                    #pragma unroll
                    for (int n = 0; n < 4; ++n) {
                        const int kvr = kv0 + n * 16 + quad * 4;
                        #pragma unroll
                        for (int r = 0; r < 4; ++r)
                            if (kvr + r > qB_abs) sB[n][r] = -1e30f;
                    }
                }
                half4 phB[4];
                #pragma unroll
                for (int n = 0; n < 4; ++n)
                    #pragma unroll
                    for (int r = 0; r < 4; ++r) {
                        const float eB = __builtin_amdgcn_exp2f(sB[n][r] * cs);
                        lsB4[r] += eB; phB[n][r] = (_Float16)eB;
                    }
                #pragma unroll
                for (int nt = 0; nt < 4; ++nt) {
                    const char* row = (const char*)&Vtlds[buf][nt * 16 + l16][0];
                    #pragma unroll
                    for (int nk = 0; nk < 4; ++nk) {
                        const int pp = (4 * nk + quad + l16 + 4 * nt) & 15;
                        half4 bv = *(const half4*)(row + pp * 8);
                        oB[nt] = __builtin_amdgcn_mfma_f32_16x16x16f16(phB[nk], bv, oB[nt], 0, 0, 0);
                    }
                }
            }
        }
        __syncthreads();   // fences staged data for u+1 AND buffer reuse at u+1
    }

    // ---- combine parity partials via LDS, normalize, store ----
    // group 0 finalizes strip A; group 1 finalizes strip B.
    // Exchange: group 1 writes its (oA, lsA); group 0 writes its (oB, lsB).
    // Layout: [strip(A=0,B=1)][wrow][lane][17] floats, stride 17 = conflict-free.
    float* ex = (float*)&Klds[0][0][0];      // reuse: 34,816 B <= 36,864 B
    const int slotsz = 64 * 17;
    {
        float* wb = ex + (g ? 0 : 4 * slotsz) + wrow * slotsz + lane * 17;
        const f32x4* po = g ? oA : oB;
        const f32x4  l4 = g ? lsA4 : lsB4;
        #pragma unroll
        for (int nt = 0; nt < 4; ++nt)
            #pragma unroll
            for (int r = 0; r < 4; ++r) wb[nt * 4 + r] = po[nt][r];
        wb[16] = (l4[0] + l4[1]) + (l4[2] + l4[3]);
    }
    __syncthreads();
    {
        const float* rb = ex + (g ? 4 * slotsz : 0) + wrow * slotsz + lane * 17;
        const f32x4* mine = g ? oB : oA;
        const f32x4  m4   = g ? lsB4 : lsA4;
        f32x4 o[4];
        #pragma unroll
        for (int nt = 0; nt < 4; ++nt)
            #pragma unroll
            for (int r = 0; r < 4; ++r) o[nt][r] = mine[nt][r] + rb[nt * 4 + r];
        float v = ((m4[0] + m4[1]) + (m4[2] + m4[3])) + rb[16];
        v += __shfl_xor(v, 16, 64);
        v += __shfl_xor(v, 32, 64);
        float linv[4];
        #pragma unroll
        for (int r = 0; r < 4; ++r)
            linv[r] = 1.0f / __shfl(v, quad * 4 + r, 64);
        const int q0s = (g ? dB : dA) * 64;
        const int qr0 = q0s + wrow * 16 + quad * 4;
        #pragma unroll
        for (int nt = 0; nt < 4; ++nt)
            #pragma unroll
            for (int r = 0; r < 4; ++r)
                Ob[(size_t)(qr0 + r) * D_ + nt * 16 + l16] = o[nt][r] * linv[r];
    }
}

extern "C" void kernel_launch(void* const* d_in, const int* in_sizes, int n_in,
                              void* d_out, int out_size, void* d_ws, size_t ws_size,
                              hipStream_t stream) {
    const float* Q = (const float*)d_in[0];
    const float* K = (const float*)d_in[1];
    const float* V = (const float*)d_in[2];
    float*       O = (float*)d_out;
    fa_fwd<<<dim3(16 * B_ * H_), dim3(512), 0, stream>>>(Q, K, V, O);
}

// Round 5
// 121.203 us; speedup vs baseline: 1.9067x; 1.0473x over previous
//
#include <hip/hip_runtime.h>
#include <stdint.h>

// B=2, H=16, L=2048, D=64 causal attention, fp32 in/out.
#define B_ 2
#define H_ 16
#define L_ 2048
#define D_ 64
#define BN 64   // KV rows per tile; also q rows per strip

typedef __attribute__((ext_vector_type(8))) _Float16 half8;
typedef __attribute__((ext_vector_type(4))) _Float16 half4;
typedef __attribute__((ext_vector_type(4))) float    f32x4;

// Round-2 structure (verified best): 256-thread block owns strip pair
// (p, 31-p); all 4 waves compute BOTH strips per staged tile (strip A while
// t <= dA), sharing K/V LDS reads; stage+prefetch at TOP of the body so the
// compute phase covers the s_waitcnt vmcnt(0) drain before s_barrier.
//
// ROUND-4 POST-MORTEM: doubling waves/SIMD (kv-parity groups, shared
// barrier) did NOT cut per-unit time -> latency is not TLP-starved; it is a
// DEVICE-WIDE PHASE-LOCK: all blocks have identical per-iteration structure
// and start together, so every block's barrier drain lands at the same
// wall-clock instant and nothing issues anywhere during it.
//
// ROUND-5 CHANGES:
//  (1) Tile-order rotation: block i processes kv tiles in order
//      w(j) = (j + i mod (dB+1)) mod (dB+1). Sum-only softmax is
//      order-invariant, so this is legal; co-resident blocks now stall at
//      uncorrelated phases and cover each other's barrier drains.
//  (2) cs = (1/8)*log2(e) folded into the fp16 Q fragment at load
//      (-16 fmul per wave-tile; exp2 consumes raw MFMA output).
//  (3) Row-sums via ones-MFMA: lsq[r] += mfma(ph[nk], ones, lsq) replaces
//      16 serial fadds per wave-tile AND the epilogue shuffle reduce.
//      Normalizer = sum of the same fp16 P used in PV (consistent).
//
// __launch_bounds__ 2nd arg is MIN BLOCKS PER CU on this hipcc (round-3
// post-mortem: (512,4) capped VGPRs at 64 and spilled). (256,2) -> cap 256.
//
// blockIdx decode (assumes round-robin i%8 -> XCD): bh = ((i>>3)&3)*8+(i&7)
// gives each XCD all 16 pairs of 4 fixed bh's -> K/V stream L2/L3-local.

__global__ __launch_bounds__(256, 2) void fa_fwd(
    const float* __restrict__ Q, const float* __restrict__ K,
    const float* __restrict__ V, float* __restrict__ O)
{
    const int i  = blockIdx.x;
    const int bh = ((i >> 3) & 3) * 8 + (i & 7);
    const int p  = i >> 5;               // 0..15
    const int dA = p;                    // small strip diagonal
    const int dB = 31 - p;               // large strip diagonal (>= 16)
    const int nT = dB + 1;               // tiles this block touches
    const int off = i % nT;              // phase-desync rotation

    const int tid  = threadIdx.x;
    const int wrow = tid >> 6;           // wave = 16-row band within each strip
    const int lane = tid & 63;
    const int l16  = lane & 15;
    const int quad = lane >> 4;

    const size_t base = (size_t)bh * (size_t)(L_ * D_);
    const float* Qb = Q + base;
    const float* Kb = K + base;
    const float* Vb = V + base;
    float*       Ob = O + base;

    // Double-buffered shared tiles (34,816 B).
    __shared__ __align__(16) _Float16 Klds [2][BN][72];  // row-major K
    __shared__ __align__(16) _Float16 Vtlds[2][D_][64];  // V^T, 8B-block swizzled

    // ---- staging: every thread stages a K quarter AND a V quarter ----
    const int srow  = tid >> 4;          // K: row 0..15 (x4)
    const int scol  = (tid & 15) * 4;    // K: col
    const int vw    = wrow;              // V: 16-row band 0..3
    const int vlane = lane;              // V: d = vlane

    float fk[16];  // K prefetch regs (float4[4])
    float fv[16];  // V prefetch regs (16 scalars)

    auto prefetch = [&](int kv0) {
        float4* kq = (float4*)fk;
        const float* kp = Kb + (size_t)kv0 * D_ + (size_t)tid * 4;
        #pragma unroll
        for (int u = 0; u < 4; ++u) kq[u] = *(const float4*)(kp + u * 1024);
        const float* vp = Vb + (size_t)(kv0 + vw * 16) * D_ + vlane;
        #pragma unroll
        for (int rr = 0; rr < 16; ++rr) fv[rr] = vp[rr * D_];
    };

    auto stage = [&](int buf) {
        const float4* kq = (const float4*)fk;
        #pragma unroll
        for (int u = 0; u < 4; ++u) {
            half4 ks;
            ks[0] = (_Float16)kq[u].x; ks[1] = (_Float16)kq[u].y;
            ks[2] = (_Float16)kq[u].z; ks[3] = (_Float16)kq[u].w;
            *(half4*)&Klds[buf][u * 16 + srow][scol] = ks;
        }
        #pragma unroll
        for (int c = 0; c < 4; ++c) {
            half4 vs;
            vs[0] = (_Float16)fv[4 * c + 0]; vs[1] = (_Float16)fv[4 * c + 1];
            vs[2] = (_Float16)fv[4 * c + 2]; vs[3] = (_Float16)fv[4 * c + 3];
            // kv>>2 = 4*vw + c; pos = (kv>>2 + d + 4*(d>>4)) & 15, d = vlane
            const int pp = ((4 * vw + c) + vlane + 4 * (vlane >> 4)) & 15;
            *(half4*)((char*)&Vtlds[buf][vlane][0] + pp * 8) = vs;
        }
    };

    // ---- per-strip state ----
    // Q fragment (pre-scaled by cs): B-operand of S^T = K.Q^T
    const float cs = 0.18033688011112042f; // (1/8) * log2(e), folded into Q
    half8 qfA[2], qfB[2];
    const int qA_abs = dA * 64 + wrow * 16 + l16;
    const int qB_abs = dB * 64 + wrow * 16 + l16;
    auto loadQ = [&](half8* qf, int q_abs) {
        #pragma unroll
        for (int c = 0; c < 2; ++c) {
            const float* pq = Qb + (size_t)q_abs * D_ + c * 32 + quad * 8;
            float4 a = *(const float4*)(pq);
            float4 b = *(const float4*)(pq + 4);
            half8 f;
            f[0] = (_Float16)(a.x * cs); f[1] = (_Float16)(a.y * cs);
            f[2] = (_Float16)(a.z * cs); f[3] = (_Float16)(a.w * cs);
            f[4] = (_Float16)(b.x * cs); f[5] = (_Float16)(b.y * cs);
            f[6] = (_Float16)(b.z * cs); f[7] = (_Float16)(b.w * cs);
            qf[c] = f;
        }
    };
    loadQ(qfA, qA_abs);
    loadQ(qfB, qB_abs);

    f32x4 oA[4], oB[4];
    #pragma unroll
    for (int n = 0; n < 4; ++n) {
        oA[n] = (f32x4){0.f, 0.f, 0.f, 0.f};
        oB[n] = (f32x4){0.f, 0.f, 0.f, 0.f};
    }
    f32x4 lsqA = (f32x4){0.f, 0.f, 0.f, 0.f};   // row sums via ones-MFMA
    f32x4 lsqB = (f32x4){0.f, 0.f, 0.f, 0.f};
    half4 one4;
    one4[0] = (_Float16)1.f; one4[1] = (_Float16)1.f;
    one4[2] = (_Float16)1.f; one4[3] = (_Float16)1.f;

    // ---- pipeline prologue (rotated tile order) ----
    const int w0 = off;
    const int w1 = (off + 1 > dB) ? 0 : off + 1;
    prefetch(w0 * BN);
    stage(0);
    prefetch(w1 * BN);
    __syncthreads();

    // ---- main loop: stage+prefetch FIRST, compute covers the vmcnt drain ----
    int t = w0;                                  // t = w(j)
    for (int j = 0; j <= dB; ++j) {
        const int buf = j & 1;

        if (j < dB)      stage(buf ^ 1);         // tile w(j+1), prefetched last iter
        if (j + 2 <= dB) {
            int tpf = t + 2;                     // w(j+2) with wrap
            if (tpf > dB) tpf -= nT;
            prefetch(tpf * BN);                  // lands during compute below
        }

        const int kv0  = t * BN;
        const bool both = (t <= dA);             // block-uniform

        if (both) {
            // ---- both strips, shared K/V LDS reads ----
            f32x4 sB[4], sA[4];
            #pragma unroll
            for (int n = 0; n < 4; ++n) {
                f32x4 aB = (f32x4){0.f, 0.f, 0.f, 0.f};
                f32x4 aA = (f32x4){0.f, 0.f, 0.f, 0.f};
                #pragma unroll
                for (int c = 0; c < 2; ++c) {
                    half8 kf = *(const half8*)&Klds[buf][n * 16 + l16][c * 32 + quad * 8];
                    aB = __builtin_amdgcn_mfma_f32_16x16x32_f16(kf, qfB[c], aB, 0, 0, 0);
                    aA = __builtin_amdgcn_mfma_f32_16x16x32_f16(kf, qfA[c], aA, 0, 0, 0);
                }
                sB[n] = aB; sA[n] = aA;
            }
            // strip A diagonal mask (t == dB impossible here: t <= dA < 16 <= dB)
            if (t == dA) {
                #pragma unroll
                for (int n = 0; n < 4; ++n) {
                    const int kvr = kv0 + n * 16 + quad * 4;
                    #pragma unroll
                    for (int r = 0; r < 4; ++r)
                        if (kvr + r > qA_abs) sA[n][r] = -1e30f;
                }
            }
            half4 phB[4], phA[4];
            #pragma unroll
            for (int n = 0; n < 4; ++n)
                #pragma unroll
                for (int r = 0; r < 4; ++r) {
                    phB[n][r] = (_Float16)__builtin_amdgcn_exp2f(sB[n][r]);
                    phA[n][r] = (_Float16)__builtin_amdgcn_exp2f(sA[n][r]);
                }
            #pragma unroll
            for (int nk = 0; nk < 4; ++nk) {
                lsqB = __builtin_amdgcn_mfma_f32_16x16x16f16(phB[nk], one4, lsqB, 0, 0, 0);
                lsqA = __builtin_amdgcn_mfma_f32_16x16x16f16(phA[nk], one4, lsqA, 0, 0, 0);
            }
            #pragma unroll
            for (int nt = 0; nt < 4; ++nt) {
                const char* row = (const char*)&Vtlds[buf][nt * 16 + l16][0];
                #pragma unroll
                for (int nk = 0; nk < 4; ++nk) {
                    const int pp = (4 * nk + quad + l16 + 4 * nt) & 15;
                    half4 bv = *(const half4*)(row + pp * 8);
                    oB[nt] = __builtin_amdgcn_mfma_f32_16x16x16f16(phB[nk], bv, oB[nt], 0, 0, 0);
                    oA[nt] = __builtin_amdgcn_mfma_f32_16x16x16f16(phA[nk], bv, oA[nt], 0, 0, 0);
                }
            }
        } else {
            // ---- strip B only ----
            f32x4 sB[4];
            #pragma unroll
            for (int n = 0; n < 4; ++n) {
                f32x4 aB = (f32x4){0.f, 0.f, 0.f, 0.f};
                #pragma unroll
                for (int c = 0; c < 2; ++c) {
                    half8 kf = *(const half8*)&Klds[buf][n * 16 + l16][c * 32 + quad * 8];
                    aB = __builtin_amdgcn_mfma_f32_16x16x32_f16(kf, qfB[c], aB, 0, 0, 0);
                }
                sB[n] = aB;
            }
            if (t == dB) {                        // strip B diagonal mask
                #pragma unroll
                for (int n = 0; n < 4; ++n) {
                    const int kvr = kv0 + n * 16 + quad * 4;
                    #pragma unroll
                    for (int r = 0; r < 4; ++r)
                        if (kvr + r > qB_abs) sB[n][r] = -1e30f;
                }
            }
            half4 phB[4];
            #pragma unroll
            for (int n = 0; n < 4; ++n)
                #pragma unroll
                for (int r = 0; r < 4; ++r)
                    phB[n][r] = (_Float16)__builtin_amdgcn_exp2f(sB[n][r]);
            #pragma unroll
            for (int nk = 0; nk < 4; ++nk)
                lsqB = __builtin_amdgcn_mfma_f32_16x16x16f16(phB[nk], one4, lsqB, 0, 0, 0);
            #pragma unroll
            for (int nt = 0; nt < 4; ++nt) {
                const char* row = (const char*)&Vtlds[buf][nt * 16 + l16][0];
                #pragma unroll
                for (int nk = 0; nk < 4; ++nk) {
                    const int pp = (4 * nk + quad + l16 + 4 * nt) & 15;
                    half4 bv = *(const half4*)(row + pp * 8);
                    oB[nt] = __builtin_amdgcn_mfma_f32_16x16x16f16(phB[nk], bv, oB[nt], 0, 0, 0);
                }
            }
        }

        if (j < dB) __syncthreads();             // uniform across all 4 waves
        t = (t + 1 > dB) ? 0 : t + 1;            // advance rotated tile index
    }

    // ---- epilogue (wave-private): normalize by MFMA row-sums, store ----
    // lsq[r] holds the full row sum for q = quad*4 + r (identical in all l16).
    auto epi = [&](const f32x4* o, f32x4 lsq, int q0s) {
        float linv[4];
        #pragma unroll
        for (int r = 0; r < 4; ++r) linv[r] = 1.0f / lsq[r];
        const int qr0 = q0s + wrow * 16 + quad * 4;
        #pragma unroll
        for (int nt = 0; nt < 4; ++nt)
            #pragma unroll
            for (int r = 0; r < 4; ++r)
                Ob[(size_t)(qr0 + r) * D_ + nt * 16 + l16] = o[nt][r] * linv[r];
    };
    epi(oA, lsqA, dA * 64);
    epi(oB, lsqB, dB * 64);
}

extern "C" void kernel_launch(void* const* d_in, const int* in_sizes, int n_in,
                              void* d_out, int out_size, void* d_ws, size_t ws_size,
                              hipStream_t stream) {
    const float* Q = (const float*)d_in[0];
    const float* K = (const float*)d_in[1];
    const float* V = (const float*)d_in[2];
    float*       O = (float*)d_out;
    fa_fwd<<<dim3(16 * B_ * H_), dim3(256), 0, stream>>>(Q, K, V, O);
}